// Round 1
// baseline (268.460 us; speedup 1.0000x reference)
//
#include <hip/hip_runtime.h>
#include <hip/hip_bf16.h>

typedef __attribute__((ext_vector_type(8))) short bf16x8;
typedef __attribute__((ext_vector_type(4))) short s16x4;
typedef __attribute__((ext_vector_type(4))) float f32x4;

__device__ __forceinline__ short f2bf(float f) {
  unsigned u = __builtin_bit_cast(unsigned, f);
  u = (u + 0x7FFFu + ((u >> 16) & 1u)) >> 16;
  return (short)u;
}

__device__ __forceinline__ void gload_lds16(const void* g, void* l) {
  __builtin_amdgcn_global_load_lds(
      (const __attribute__((address_space(1))) void*)g,
      (__attribute__((address_space(3))) void*)l, 16, 0, 0);
}

// ---------------------------------------------------------------- prep kernels

// x (B,240,512) fp32 -> xb (B*256,512) bf16, zero-padded rows 240..255
__global__ void k_convert_x(const float* __restrict__ x, short* __restrict__ xb) {
  int i = blockIdx.x * 256 + threadIdx.x;      // group of 4 elements
  int c4 = i & 127;
  int row = i >> 7;                            // 0..32767
  int b = row >> 8, t = row & 255;
  s16x4 o = {0, 0, 0, 0};
  if (t < 240) {
    const float4 v = *(const float4*)(x + (size_t)(b * 240 + t) * 512 + c4 * 4);
    o.x = f2bf(v.x); o.y = f2bf(v.y); o.z = f2bf(v.z); o.w = f2bf(v.w);
  }
  *(s16x4*)(xb + (size_t)row * 512 + c4 * 4) = o;
}

// W (K,N) fp32 -> Wt (N,K) bf16
__global__ void k_transpose_w(const float* __restrict__ W, short* __restrict__ Wt,
                              int K, int N) {
  int i = blockIdx.x * 256 + threadIdx.x;      // n*K + k
  if (i >= K * N) return;
  int k = i % K, n = i / K;
  Wt[i] = f2bf(W[(size_t)k * N + n]);
}

// rel_bias_table (961,16) -> biasM (16,256,256) fp32
__global__ void k_bias(const float* __restrict__ table, float* __restrict__ biasM) {
  int i = blockIdx.x * 256 + threadIdx.x;      // h*65536 + q*256 + k
  int k = i & 255, q = (i >> 8) & 255, h = i >> 16;
  int qi = q >> 4, qj = q & 15, ki = k >> 4, kj = k & 15;
  int idx = (qi - ki + 15) * 31 + (qj - kj + 15);
  biasM[i] = table[idx * 16 + h];
}

// ---------------------------------------------------------------- GEMM
// C = A(M x 512) * Bt(N x 512)^T + bias ; 128x128 tile, 4 waves, BK=32
// MODE 0: QKV epilogue (scatter to Q*scale/K/V bf16, (B,H,256,32) layout)
// MODE 1: proj epilogue (fp32 out, drop padded rows)
template <int MODE>
__global__ __launch_bounds__(256, 2)
void k_gemm(const short* __restrict__ A, const short* __restrict__ Bt,
            const float* __restrict__ bias,
            short* __restrict__ qo, short* __restrict__ ko, short* __restrict__ vo,
            float* __restrict__ fo) {
  __shared__ alignas(16) short lds[2][8][512];   // frag-ordered: [blk][lane*8]
  const int lane = threadIdx.x & 63;
  const int w = threadIdx.x >> 6;
  const int n0 = blockIdx.x * 128;
  const int m0 = blockIdx.y * 128;
  const int wr = w >> 1, wc = w & 1;
  const int arow = lane & 15;
  const int kc8 = (lane >> 4) * 8;

  f32x4 acc[4][4] = {};

  for (int kt = 0; kt < 16; ++kt) {
    const int k0 = kt * 32;
#pragma unroll
    for (int s = 0; s < 2; ++s) {
      const int blk = 2 * w + s;
      gload_lds16(A + (size_t)(m0 + blk * 16 + arow) * 512 + k0 + kc8, &lds[0][blk][0]);
      gload_lds16(Bt + (size_t)(n0 + blk * 16 + arow) * 512 + k0 + kc8, &lds[1][blk][0]);
    }
    __syncthreads();
    bf16x8 af[4], bfr[4];
#pragma unroll
    for (int i = 0; i < 4; ++i) af[i] = *(const bf16x8*)&lds[0][wr * 4 + i][lane * 8];
#pragma unroll
    for (int j = 0; j < 4; ++j) bfr[j] = *(const bf16x8*)&lds[1][wc * 4 + j][lane * 8];
#pragma unroll
    for (int i = 0; i < 4; ++i)
#pragma unroll
      for (int j = 0; j < 4; ++j)
        acc[i][j] = __builtin_amdgcn_mfma_f32_16x16x32_bf16(af[i], bfr[j], acc[i][j], 0, 0, 0);
    __syncthreads();
  }

  const float sc = 0.17677669529663687f;   // 1/sqrt(32)
#pragma unroll
  for (int i = 0; i < 4; ++i) {
    const int mbase = m0 + (wr * 4 + i) * 16 + ((lane >> 4) << 2);
#pragma unroll
    for (int j = 0; j < 4; ++j) {
      const int c = n0 + (wc * 4 + j) * 16 + arow;
      const float bv = bias[c];
#pragma unroll
      for (int r = 0; r < 4; ++r) {
        float val = acc[i][j][r] + bv;
        const int mm = mbase + r;
        const int bb = mm >> 8, tt = mm & 255;
        if (MODE == 0) {
          const int part = c >> 9;
          const int hh = (c >> 5) & 15;
          const int dd = c & 31;
          const size_t off = ((size_t)(bb * 16 + hh) * 256 + tt) * 32 + dd;
          if (part == 0)       qo[off] = f2bf(val * sc);
          else if (part == 1)  ko[off] = f2bf(val);
          else                 vo[off] = f2bf(val);
        } else {
          if (tt < 240) fo[(size_t)(bb * 240 + tt) * 512 + c] = val;
        }
      }
    }
  }
}

// ---------------------------------------------------------------- attention
// One WG (4 waves) per (b,h). Keys 240..255 are exactly col-tile j=15 -> skipped.
__global__ __launch_bounds__(256, 2)
void k_attn(const short* __restrict__ Qg, const short* __restrict__ Kg,
            const short* __restrict__ Vg, const float* __restrict__ biasM,
            short* __restrict__ O) {
  __shared__ alignas(16) short ldsK[15 * 512];      // frag-ordered K, 15 tiles
  __shared__ alignas(16) short ldsV[256 * 32];      // linear V (t-major)
  __shared__ alignas(16) short ldsP[4][16 * 264];   // per-wave P, padded stride
  const int lane = threadIdx.x & 63;
  const int w = threadIdx.x >> 6;
  const int bh = blockIdx.x;
  const int h = bh & 15;
  const int b = bh >> 4;
  const short* Qb = Qg + (size_t)bh * 8192;
  const short* Kb = Kg + (size_t)bh * 8192;
  const short* Vb = Vg + (size_t)bh * 8192;
  const int arow = lane & 15;
  const int kc8 = (lane >> 4) * 8;
  const int rbase = (lane >> 4) << 2;

#pragma unroll
  for (int kt = 0; kt < 15; ++kt)
    if ((kt & 3) == w)
      gload_lds16(Kb + (kt * 16 + arow) * 32 + kc8, &ldsK[kt * 512]);
#pragma unroll
  for (int i = 0; i < 16; ++i)
    if ((i >> 2) == w)
      gload_lds16(Vb + i * 512 + lane * 8, &ldsV[i * 512]);

  bf16x8 qf[4];
#pragma unroll
  for (int i = 0; i < 4; ++i)
    qf[i] = *(const bf16x8*)(Qb + ((w * 4 + i) * 16 + arow) * 32 + kc8);

  {  // zero masked P columns 240..255 (all 16 rows) in this wave's buffer
    s16x4 z = {0, 0, 0, 0};
    *(s16x4*)&ldsP[w][arow * 264 + 240 + rbase] = z;
  }
  __syncthreads();

  // V register fragments: vf[s][dt] holds V[s*32+(lane>>4)*8+j][dt*16+arow]
  bf16x8 vf[8][2];
#pragma unroll
  for (int s = 0; s < 8; ++s)
#pragma unroll
    for (int dt = 0; dt < 2; ++dt) {
      bf16x8 v;
#pragma unroll
      for (int jj = 0; jj < 8; ++jj)
        v[jj] = ldsV[(s * 32 + (lane >> 4) * 8 + jj) * 32 + dt * 16 + arow];
      vf[s][dt] = v;
    }

  const f32x4 zf = {0.f, 0.f, 0.f, 0.f};
#pragma unroll
  for (int qt = 0; qt < 4; ++qt) {
    f32x4 sacc[15];
#pragma unroll
    for (int j = 0; j < 15; ++j) {
      bf16x8 kf = *(const bf16x8*)&ldsK[j * 512 + lane * 8];
      sacc[j] = __builtin_amdgcn_mfma_f32_16x16x32_bf16(qf[qt], kf, zf, 0, 0, 0);
    }
    const int q0 = (w * 4 + qt) * 16;
    const float* bp = biasM + ((size_t)h * 256 + q0 + rbase) * 256 + arow;
    float mrow[4] = {-1e30f, -1e30f, -1e30f, -1e30f};
#pragma unroll
    for (int j = 0; j < 15; ++j)
#pragma unroll
      for (int r = 0; r < 4; ++r) {
        float v = sacc[j][r] + bp[r * 256 + j * 16];
        sacc[j][r] = v;
        mrow[r] = fmaxf(mrow[r], v);
      }
#pragma unroll
    for (int d = 1; d < 16; d <<= 1)
#pragma unroll
      for (int r = 0; r < 4; ++r)
        mrow[r] = fmaxf(mrow[r], __shfl_xor(mrow[r], d, 64));
    float ssum[4] = {0.f, 0.f, 0.f, 0.f};
#pragma unroll
    for (int j = 0; j < 15; ++j)
#pragma unroll
      for (int r = 0; r < 4; ++r) {
        float p = exp2f((sacc[j][r] - mrow[r]) * 1.4426950408889634f);
        sacc[j][r] = p;
        ssum[r] += p;
      }
#pragma unroll
    for (int d = 1; d < 16; d <<= 1)
#pragma unroll
      for (int r = 0; r < 4; ++r)
        ssum[r] += __shfl_xor(ssum[r], d, 64);
    // transpose P to A-frag layout via padded LDS (row stride 264 el = 528 B)
#pragma unroll
    for (int j = 0; j < 15; ++j)
#pragma unroll
      for (int r = 0; r < 4; ++r)
        ldsP[w][(rbase + r) * 264 + j * 16 + arow] = f2bf(sacc[j][r]);
    f32x4 oacc[2] = {};
#pragma unroll
    for (int s = 0; s < 8; ++s) {
      bf16x8 pf = *(const bf16x8*)&ldsP[w][arow * 264 + s * 32 + kc8];
#pragma unroll
      for (int dt = 0; dt < 2; ++dt)
        oacc[dt] = __builtin_amdgcn_mfma_f32_16x16x32_bf16(pf, vf[s][dt], oacc[dt], 0, 0, 0);
    }
#pragma unroll
    for (int dt = 0; dt < 2; ++dt)
#pragma unroll
      for (int r = 0; r < 4; ++r) {
        float o = oacc[dt][r] / ssum[r];
        O[((size_t)(b * 256 + q0 + rbase + r)) * 512 + h * 32 + dt * 16 + arow] = f2bf(o);
      }
  }
}

// ---------------------------------------------------------------- launch

extern "C" void kernel_launch(void* const* d_in, const int* in_sizes, int n_in,
                              void* d_out, int out_size, void* d_ws, size_t ws_size,
                              hipStream_t stream) {
  const float* x      = (const float*)d_in[0];
  const float* qkv_w  = (const float*)d_in[1];
  const float* qkv_b  = (const float*)d_in[2];
  const float* proj_w = (const float*)d_in[3];
  const float* proj_b = (const float*)d_in[4];
  const float* table  = (const float*)d_in[5];
  float* out = (float*)d_out;

  char* ws = (char*)d_ws;
  short* xb      = (short*)(ws);                 // 33,554,432 B (reused as attn_out)
  short* Qg      = (short*)(ws + 33554432u);     // 33,554,432 B
  short* Kg      = (short*)(ws + 67108864u);     // 33,554,432 B
  short* Vg      = (short*)(ws + 100663296u);    // 33,554,432 B
  float* biasM   = (float*)(ws + 134217728u);    //  4,194,304 B
  short* qkv_wt  = (short*)(ws + 138412032u);    //  1,572,864 B
  short* proj_wt = (short*)(ws + 139984896u);    //    524,288 B
  // total 140,509,184 B required in d_ws

  k_convert_x<<<16384, 256, 0, stream>>>(x, xb);
  k_transpose_w<<<(1536 * 512) / 256, 256, 0, stream>>>(qkv_w, qkv_wt, 512, 1536);
  k_transpose_w<<<(512 * 512) / 256, 256, 0, stream>>>(proj_w, proj_wt, 512, 512);
  k_bias<<<4096, 256, 0, stream>>>(table, biasM);
  k_gemm<0><<<dim3(12, 256), 256, 0, stream>>>(xb, qkv_wt, qkv_b, Qg, Kg, Vg, nullptr);
  k_attn<<<2048, 256, 0, stream>>>(Qg, Kg, Vg, biasM, xb);
  k_gemm<1><<<dim3(4, 256), 256, 0, stream>>>(xb, proj_wt, proj_b, nullptr, nullptr, nullptr, out);
}